// Round 1
// 1280.242 us; speedup vs baseline: 2.7391x; 2.7391x over previous
//
#include <hip/hip_runtime.h>

#define S_N 20000
#define E_N 10000
#define K_N 128
#define D_N 128
#define NEK 40000
#define NSE 500000
#define B_N 2048

// ---- GEMM: C[r][c] = sum_k A[r][k] * W[k][c]; A rows x 128, W 128x128 ----
#define KT 32
__global__ __launch_bounds__(256) void k_gemm(const float* __restrict__ A, const float* __restrict__ W,
                                              float* __restrict__ C, int rows){
  __shared__ float As[KT][132];
  __shared__ float Bs[KT][132];
  int t = threadIdx.x;
  int tx = t & 15, ty = t >> 4;
  int r0 = blockIdx.x * 128;
  float acc[8][8];
  #pragma unroll
  for(int i=0;i<8;i++)
    #pragma unroll
    for(int j=0;j<8;j++) acc[i][j]=0.f;

  for(int kt=0; kt<128; kt+=KT){
    for(int i=t; i<KT*128; i+=256){       // A tile, store transposed [k][r]
      int k = i & (KT-1), r = i / KT;
      int gr = r0 + r;
      As[k][r] = (gr < rows) ? A[(size_t)gr*128 + kt + k] : 0.f;
    }
    for(int i=t; i<KT*128; i+=256){       // W tile [k][c]
      int c = i & 127, k = i >> 7;
      Bs[k][c] = W[(size_t)(kt+k)*128 + c];
    }
    __syncthreads();
    #pragma unroll
    for(int k=0;k<KT;k++){
      float4 a0 = *(const float4*)&As[k][ty*8];
      float4 a1 = *(const float4*)&As[k][ty*8+4];
      float4 b0 = *(const float4*)&Bs[k][tx*8];
      float4 b1 = *(const float4*)&Bs[k][tx*8+4];
      float av[8] = {a0.x,a0.y,a0.z,a0.w,a1.x,a1.y,a1.z,a1.w};
      float bv[8] = {b0.x,b0.y,b0.z,b0.w,b1.x,b1.y,b1.z,b1.w};
      #pragma unroll
      for(int i=0;i<8;i++)
        #pragma unroll
        for(int j=0;j<8;j++) acc[i][j] += av[i]*bv[j];
    }
    __syncthreads();
  }
  #pragma unroll
  for(int i=0;i<8;i++){
    int r = r0 + ty*8 + i;
    if(r < rows){
      float4 s0 = {acc[i][0],acc[i][1],acc[i][2],acc[i][3]};
      float4 s1 = {acc[i][4],acc[i][5],acc[i][6],acc[i][7]};
      *(float4*)&C[(size_t)r*128 + tx*8]     = s0;
      *(float4*)&C[(size_t)r*128 + tx*8 + 4] = s1;
    }
  }
}

// ---- CSR build: histogram -> scan -> fill ----
__global__ __launch_bounds__(256) void k_hist(const int* __restrict__ key, int m, int kb, int* __restrict__ cnt){
  int i = blockIdx.x*256 + threadIdx.x;
  if(i < m) atomicAdd(cnt + (key[i] - kb), 1);
}

// single-block exclusive scan; writes rowptr[0..n] and cursor[0..n-1]
__global__ __launch_bounds__(1024) void k_scan(const int* __restrict__ cnt, int n,
                                               int* __restrict__ rp, int* __restrict__ cur){
  __shared__ int part[1024];
  int t = threadIdx.x;
  int chunk = (n + 1023) >> 10;
  int b0 = t * chunk;
  int s = 0;
  for(int i=0;i<chunk;i++){ int idx=b0+i; if(idx<n) s += cnt[idx]; }
  part[t] = s;
  __syncthreads();
  for(int off=1; off<1024; off<<=1){
    int v = (t>=off) ? part[t-off] : 0;
    __syncthreads();
    part[t] += v;
    __syncthreads();
  }
  int run = t ? part[t-1] : 0;
  for(int i=0;i<chunk;i++){
    int idx=b0+i;
    if(idx<n){ int c = cnt[idx]; rp[idx]=run; cur[idx]=run; run += c; }
  }
  if(t==0) rp[n] = part[1023];
}

__global__ __launch_bounds__(256) void k_fill(const int* __restrict__ key, const int* __restrict__ val,
                                              int m, int kb, int* __restrict__ cur, int* __restrict__ col){
  int i = blockIdx.x*256 + threadIdx.x;
  if(i < m){
    int pos = atomicAdd(cur + (key[i] - kb), 1);
    col[pos] = val[i];
  }
}

// ---- wa[gl][h][k] = sum_c GW[gl][k][c] * Ga[gl][h*128+c], 16 vectors of 128 ----
__global__ __launch_bounds__(256) void k_wa(const float* __restrict__ GW, const float* __restrict__ Ga,
                                            float* __restrict__ wa){
  int w = (blockIdx.x*256 + threadIdx.x) >> 6;
  int lane = threadIdx.x & 63;
  if(w >= 2048) return;
  int k = w & 127, h = (w>>7)&1, gl = w>>8;
  const float* grow = GW + ((size_t)gl*128 + k)*128;
  const float* ga   = Ga + (size_t)gl*256 + h*128;
  float2 g2 = ((const float2*)grow)[lane];
  float2 av = ((const float2*)ga)[lane];
  float s = g2.x*av.x + g2.y*av.y;
  #pragma unroll
  for(int off=32; off; off>>=1) s += __shfl_down(s, off);
  if(lane==0) wa[w] = s;
}

// ---- p[i]=h_src[i]·wa1, q[j]=h_dst[j]·wa2 — wave per row ----
__global__ __launch_bounds__(256) void k_pq(const float* __restrict__ hs, int ns, float* __restrict__ pout,
                                            const float* __restrict__ hd, int nd, float* __restrict__ qout,
                                            const float* __restrict__ wa1, const float* __restrict__ wa2){
  int w = (blockIdx.x*256 + threadIdx.x) >> 6;
  int lane = threadIdx.x & 63;
  const float* h; const float* v; float* o; int r;
  if(w < ns){ h = hs; v = wa1; o = pout; r = w; }
  else { r = w - ns; if(r >= nd) return; h = hd; v = wa2; o = qout; }
  float2 hv = ((const float2*)(h + (size_t)r*128))[lane];
  float2 vv = ((const float2*)v)[lane];
  float s = hv.x*vv.x + hv.y*vv.y;
  #pragma unroll
  for(int off=32; off; off>>=1) s += __shfl_down(s, off);
  if(lane==0) o[r] = s;
}

// ---- fused segment softmax-aggregate: out[row] (= or +=) (Σ exp(p[s]+q[row])·z[s]) / Σ exp
// NW=1: 4 rows/block, one wave each.  NW>1: one row/block, NW waves split edges, LDS combine.
template<int NW>
__global__ __launch_bounds__(NW==1 ? 256 : 64*NW)
void k_seg(const float* __restrict__ z, const float* __restrict__ p, const float* __restrict__ q,
           const int* __restrict__ rowptr, const int* __restrict__ col,
           int ndst, float* __restrict__ out, int accum){
  int lane = threadIdx.x & 63;
  int wid  = threadIdx.x >> 6;
  int row;
  if(NW==1){ row = blockIdx.x*4 + wid; if(row >= ndst) return; }
  else     { row = blockIdx.x; }
  int e0 = rowptr[row], e1 = rowptr[row+1];
  float qd = q[row];
  float accx=0.f, accy=0.f, den=0.f;
  int e = e0 + (NW==1 ? 0 : wid);
  const int step = (NW==1 ? 1 : NW);
  // unroll-2: two independent gathers in flight
  while(e + step < e1){
    int sA = col[e], sB = col[e+step];
    float pA = p[sA], pB = p[sB];
    float2 zA = ((const float2*)(z + (size_t)sA*128))[lane];
    float2 zB = ((const float2*)(z + (size_t)sB*128))[lane];
    float xA = expf(pA + qd), xB = expf(pB + qd);
    accx += xA*zA.x; accy += xA*zA.y; den += xA;
    accx += xB*zB.x; accy += xB*zB.y; den += xB;
    e += 2*step;
  }
  if(e < e1){
    int sA = col[e];
    float xA = expf(p[sA] + qd);
    float2 zA = ((const float2*)(z + (size_t)sA*128))[lane];
    accx += xA*zA.x; accy += xA*zA.y; den += xA;
  }
  if constexpr (NW > 1){
    __shared__ float red[NW][130];
    red[wid][2*lane]   = accx;
    red[wid][2*lane+1] = accy;
    if(lane==0) red[wid][128] = den;
    __syncthreads();
    if(wid != 0) return;
    accx = 0.f; accy = 0.f; den = 0.f;
    #pragma unroll
    for(int i=0;i<NW;i++){ accx += red[i][2*lane]; accy += red[i][2*lane+1]; den += red[i][128]; }
  }
  float inv = den > 0.f ? 1.f/den : 0.f;
  float ox = accx*inv, oy = accy*inv;
  float* o = out + (size_t)row*128;
  if(accum){ o[2*lane] += ox; o[2*lane+1] += oy; }
  else     { o[2*lane]  = ox; o[2*lane+1]  = oy; }
}

// ---- per-exercise gate: sc = softmax([s1,s2]); ex += sc0*Bx + sc1*Cx ----
__global__ __launch_bounds__(256) void k_ex_update(float* __restrict__ ex, const float* __restrict__ Bx,
     const float* __restrict__ Cx, const float* __restrict__ Fw, const float* __restrict__ Fb){
  int w = (blockIdx.x*256 + threadIdx.x) >> 6;
  int lane = threadIdx.x & 63;
  if(w >= E_N) return;
  float* er = ex + (size_t)w*128;
  const float* br = Bx + (size_t)w*128;
  const float* cr = Cx + (size_t)w*128;
  float e0 = er[lane], e1 = er[lane+64];
  float b0 = br[lane], b1 = br[lane+64];
  float c0 = cr[lane], c1 = cr[lane+64];
  float s1 = e0*Fw[lane]     + e1*Fw[lane+64]
           + b0*Fw[lane+128] + b1*Fw[lane+192];
  float s2 = e0*Fw[256+lane]     + e1*Fw[256+lane+64]
           + c0*Fw[256+lane+128] + c1*Fw[256+lane+192];
  #pragma unroll
  for(int off=32; off; off>>=1){ s1 += __shfl_down(s1,off); s2 += __shfl_down(s2,off); }
  s1 = __shfl(s1, 0) + Fb[0];
  s2 = __shfl(s2, 0) + Fb[1];
  float mx = fmaxf(s1,s2);
  float pp = expf(s1-mx), qq = expf(s2-mx);
  float inv = 1.f/(pp+qq);
  er[lane]    = e0 + (pp*inv)*b0 + (qq*inv)*c0;
  er[lane+64] = e1 + (pp*inv)*b1 + (qq*inv)*c1;
}

// ---- broadcast output (f32): wave per row; out[b][i][:] = emb[use_ids? ids[b] : i][:] ----
__global__ __launch_bounds__(256) void k_out(const float* __restrict__ emb, const int* __restrict__ ids,
                                             float* __restrict__ out, int use_ids){
  int r = (blockIdx.x*256 + threadIdx.x) >> 6;   // output row in [0, B*128)
  int lane = threadIdx.x & 63;
  if(r >= B_N*128) return;
  int b = r >> 7, i = r & 127;
  int srow = use_ids ? ids[b] : i;
  float2 v = ((const float2*)(emb + (size_t)srow*128))[lane];
  ((float2*)(out + (size_t)r*128))[lane] = v;
}

__global__ void k_out_disc(const float* __restrict__ disc, const int* __restrict__ eid, float* __restrict__ out){
  int b = blockIdx.x*256 + threadIdx.x;
  if(b < B_N) out[b] = disc[eid[b]];
}

extern "C" void kernel_launch(void* const* d_in, const int* in_sizes, int n_in,
                              void* d_out, int out_size, void* d_ws, size_t ws_size,
                              hipStream_t stream){
  (void)in_sizes; (void)out_size; (void)ws_size;
  const float* stu_emb  = (const float*)d_in[0];
  const float* exer_emb = (const float*)d_in[1];
  const float* kn_emb   = (const float*)d_in[2];
  const float* disc_emb = (const float*)d_in[3];
  const float* GW = (const float*)d_in[4];
  const float* Ga = (const float*)d_in[5];
  const float* Fw = (const float*)d_in[6];
  const float* Fb = (const float*)d_in[7];
  int base = n_in - 6;
  const int* sid    = (const int*)d_in[base];
  const int* eid    = (const int*)d_in[base+1];
  const int* ek_src = (const int*)d_in[base+2];
  const int* ek_dst = (const int*)d_in[base+3];
  const int* se_src = (const int*)d_in[base+4];
  const int* se_dst = (const int*)d_in[base+5];

  char* w = (char*)d_ws;
  size_t off = 0;
  auto alloc = [&](size_t bytes)->char*{ char* p = w + off; off += (bytes + 255) & ~(size_t)255; return p; };
  float* st_f = (float*)alloc((size_t)S_N*D_N*4);
  float* ex_f = (float*)alloc((size_t)E_N*D_N*4);
  float* kn_f = (float*)alloc((size_t)K_N*D_N*4);
  float* Bx   = (float*)alloc((size_t)E_N*D_N*4);
  float* Cx   = (float*)alloc((size_t)E_N*D_N*4);
  float* z    = (float*)alloc((size_t)(E_N+S_N)*D_N*4);   // node-indexed: ex at 0, kn/st at E_N
  float* p    = (float*)alloc((size_t)(E_N+S_N)*4);       // node-indexed src scores
  float* q    = (float*)alloc((size_t)S_N*4);             // row-indexed dst scores
  float* wa   = (float*)alloc((size_t)16*128*4);          // [gl][h][k]
  int*   cnt  = (int*)alloc((size_t)(2*E_N+K_N+S_N)*4);
  int*   rp   = (int*)alloc((size_t)(2*(E_N+1)+(K_N+1)+(S_N+1))*4);
  int*   cur  = (int*)alloc((size_t)(2*E_N+K_N+S_N)*4);
  int*   col  = (int*)alloc((size_t)(2*NEK+2*NSE)*4);

  int* cnt_eke = cnt;                 // ek grouped by ex  (E_N)
  int* cnt_ekk = cnt + E_N;           // ek grouped by kn  (K_N)
  int* cnt_see = cnt + E_N + K_N;     // se grouped by ex  (E_N)
  int* cnt_ses = cnt + 2*E_N + K_N;   // se grouped by st  (S_N)
  int* cur_eke = cur;
  int* cur_ekk = cur + E_N;
  int* cur_see = cur + E_N + K_N;
  int* cur_ses = cur + 2*E_N + K_N;
  int* rp_eke = rp;
  int* rp_ekk = rp + (E_N+1);
  int* rp_see = rp + (E_N+1) + (K_N+1);
  int* rp_ses = rp + 2*(E_N+1) + (K_N+1);
  int* col_eke = col;
  int* col_ekk = col + NEK;
  int* col_see = col + 2*NEK;
  int* col_ses = col + 2*NEK + NSE;

  hipMemcpyAsync(st_f, stu_emb,  (size_t)S_N*D_N*4, hipMemcpyDeviceToDevice, stream);
  hipMemcpyAsync(ex_f, exer_emb, (size_t)E_N*D_N*4, hipMemcpyDeviceToDevice, stream);
  hipMemcpyAsync(kn_f, kn_emb,   (size_t)K_N*D_N*4, hipMemcpyDeviceToDevice, stream);

  // ---- CSR build (once; reused by both layers) ----
  hipMemsetAsync(cnt, 0, (size_t)(2*E_N+K_N+S_N)*4, stream);
  const int gb_ek = (NEK+255)/256, gb_se = (NSE+255)/256;
  k_hist<<<gb_ek,256,0,stream>>>(ek_src, NEK, 0,   cnt_eke);
  k_hist<<<gb_ek,256,0,stream>>>(ek_dst, NEK, E_N, cnt_ekk);
  k_hist<<<gb_se,256,0,stream>>>(se_src, NSE, 0,   cnt_see);
  k_hist<<<gb_se,256,0,stream>>>(se_dst, NSE, E_N, cnt_ses);
  k_scan<<<1,1024,0,stream>>>(cnt_eke, E_N, rp_eke, cur_eke);
  k_scan<<<1,1024,0,stream>>>(cnt_ekk, K_N, rp_ekk, cur_ekk);
  k_scan<<<1,1024,0,stream>>>(cnt_see, E_N, rp_see, cur_see);
  k_scan<<<1,1024,0,stream>>>(cnt_ses, S_N, rp_ses, cur_ses);
  k_fill<<<gb_ek,256,0,stream>>>(ek_src, ek_dst, NEK, 0,   cur_eke, col_eke);
  k_fill<<<gb_ek,256,0,stream>>>(ek_dst, ek_src, NEK, E_N, cur_ekk, col_ekk);
  k_fill<<<gb_se,256,0,stream>>>(se_src, se_dst, NSE, 0,   cur_see, col_see);
  k_fill<<<gb_se,256,0,stream>>>(se_dst, se_src, NSE, E_N, cur_ses, col_ses);
  k_wa<<<512,256,0,stream>>>(GW, Ga, wa);

  const int gx_ex = (E_N+127)/128, gx_st = (S_N+127)/128;

  for(int l=0; l<2; l++){
    int gl;
    {// efk: src=kn, dst=ex -> Bx (write)       [gate l*4+1]
      gl = l*4+1;
      k_gemm<<<1,256,0,stream>>>(kn_f, GW + (size_t)gl*D_N*D_N, z + (size_t)E_N*D_N, K_N);
      k_pq<<<(K_N+E_N+3)/4,256,0,stream>>>(kn_f, K_N, p+E_N, ex_f, E_N, q, wa+gl*256, wa+gl*256+128);
      k_seg<1><<<(E_N+3)/4,256,0,stream>>>(z, p, q, rp_eke, col_eke, E_N, Bx, 0);
    }
    {// kfe: src=ex, dst=kn -> kn_f += (s3==1)  [gate l*4+0]
      gl = l*4;
      k_gemm<<<gx_ex,256,0,stream>>>(ex_f, GW + (size_t)gl*D_N*D_N, z, E_N);
      k_pq<<<(E_N+K_N+3)/4,256,0,stream>>>(ex_f, E_N, p, kn_f, K_N, q, wa+gl*256, wa+gl*256+128);
      k_seg<8><<<K_N,512,0,stream>>>(z, p, q, rp_ekk, col_ekk, K_N, kn_f, 1);
    }
    {// efu: src=st, dst=ex -> Cx (write)       [gate l*4+3]
      gl = l*4+3;
      k_gemm<<<gx_st,256,0,stream>>>(st_f, GW + (size_t)gl*D_N*D_N, z + (size_t)E_N*D_N, S_N);
      k_pq<<<(S_N+E_N+3)/4,256,0,stream>>>(st_f, S_N, p+E_N, ex_f, E_N, q, wa+gl*256, wa+gl*256+128);
      k_seg<1><<<(E_N+3)/4,256,0,stream>>>(z, p, q, rp_see, col_see, E_N, Cx, 0);
    }
    {// ufe: src=ex, dst=st -> st_f +=          [gate l*4+2]
      gl = l*4+2;
      k_gemm<<<gx_ex,256,0,stream>>>(ex_f, GW + (size_t)gl*D_N*D_N, z, E_N);
      k_pq<<<(E_N+S_N+3)/4,256,0,stream>>>(ex_f, E_N, p, st_f, S_N, q, wa+gl*256, wa+gl*256+128);
      k_seg<1><<<(S_N+3)/4,256,0,stream>>>(z, p, q, rp_ses, col_ses, S_N, st_f, 1);
    }
    k_ex_update<<<(E_N*64)/256,256,0,stream>>>(ex_f, Bx, Cx, Fw + (size_t)l*3*2*D_N, Fb + (size_t)l*3);
  }

  float* out  = (float*)d_out;                 // f32 output, reference dtype
  float* out0 = out;                           // stu_ts  (B,D,D)
  float* out1 = out0 + (size_t)B_N*D_N*D_N;    // exer_ts (B,D,D)
  float* out2 = out1 + (size_t)B_N*D_N*D_N;    // disc    (B,1)
  float* out3 = out2 + (size_t)B_N;            // kn_ts   (B,K,D)
  int ob = (B_N*128*64)/256;
  k_out<<<ob,256,0,stream>>>(st_f, sid, out0, 1);
  k_out<<<ob,256,0,stream>>>(ex_f, eid, out1, 1);
  k_out_disc<<<(B_N+255)/256,256,0,stream>>>(disc_emb, eid, out2);
  k_out<<<ob,256,0,stream>>>(kn_f, sid, out3, 0);
}

// Round 2
// 926.468 us; speedup vs baseline: 3.7850x; 1.3819x over previous
//
#include <hip/hip_runtime.h>

#define S_N 20000
#define E_N 10000
#define K_N 128
#define D_N 128
#define NEK 40000
#define NSE 500000
#define B_N 2048

struct GSet { const float* A; const float* W; const float* a1; float* C; float* P; int rows; };
struct SSet { const float* z; const float* p; const int* rowptr; const int* col; const float* base; float* out; int ndst; };
struct CSet { const int* cnt; int n; int* rp; int* cur; };

// ---- batched GEMM: C[r][c] = sum_k A[r][k]*W[k][c]; epilogue p[r] = z[r]·a1 ----
#define KT 32
__global__ __launch_bounds__(256) void k_gemm(GSet g0, GSet g1, GSet g2, GSet g3){
  GSet g = g0;
  if(blockIdx.y==1) g=g1; else if(blockIdx.y==2) g=g2; else if(blockIdx.y==3) g=g3;
  int r0 = blockIdx.x * 128;
  if(r0 >= g.rows) return;
  __shared__ float As[KT][132];
  __shared__ float Bs[KT][132];
  int t = threadIdx.x;
  int tx = t & 15, ty = t >> 4;
  float acc[8][8];
  #pragma unroll
  for(int i=0;i<8;i++)
    #pragma unroll
    for(int j=0;j<8;j++) acc[i][j]=0.f;

  for(int kt=0; kt<128; kt+=KT){
    for(int i=t; i<KT*128; i+=256){       // A tile, transposed [k][r]
      int k = i & (KT-1), r = i / KT;
      int gr = r0 + r;
      As[k][r] = (gr < g.rows) ? g.A[(size_t)gr*128 + kt + k] : 0.f;
    }
    for(int i=t; i<KT*128; i+=256){       // W tile [k][c]
      int c = i & 127, k = i >> 7;
      Bs[k][c] = g.W[(size_t)(kt+k)*128 + c];
    }
    __syncthreads();
    #pragma unroll
    for(int k=0;k<KT;k++){
      float4 a0 = *(const float4*)&As[k][ty*8];
      float4 a1 = *(const float4*)&As[k][ty*8+4];
      float4 b0 = *(const float4*)&Bs[k][tx*8];
      float4 b1 = *(const float4*)&Bs[k][tx*8+4];
      float av[8] = {a0.x,a0.y,a0.z,a0.w,a1.x,a1.y,a1.z,a1.w};
      float bv[8] = {b0.x,b0.y,b0.z,b0.w,b1.x,b1.y,b1.z,b1.w};
      #pragma unroll
      for(int i=0;i<8;i++)
        #pragma unroll
        for(int j=0;j<8;j++) acc[i][j] += av[i]*bv[j];
    }
    __syncthreads();
  }
  #pragma unroll
  for(int i=0;i<8;i++){
    int r = r0 + ty*8 + i;
    if(r < g.rows){
      float4 s0 = {acc[i][0],acc[i][1],acc[i][2],acc[i][3]};
      float4 s1 = {acc[i][4],acc[i][5],acc[i][6],acc[i][7]};
      *(float4*)&g.C[(size_t)r*128 + tx*8]     = s0;
      *(float4*)&g.C[(size_t)r*128 + tx*8 + 4] = s1;
    }
  }
  // p epilogue: p[r] = sum_c z[r][c]*a1[c]; reduce across tx (16-lane groups)
  float4 w0 = ((const float4*)g.a1)[tx*2];
  float4 w1 = ((const float4*)g.a1)[tx*2+1];
  #pragma unroll
  for(int i=0;i<8;i++){
    float s = acc[i][0]*w0.x + acc[i][1]*w0.y + acc[i][2]*w0.z + acc[i][3]*w0.w
            + acc[i][4]*w1.x + acc[i][5]*w1.y + acc[i][6]*w1.z + acc[i][7]*w1.w;
    s += __shfl_xor(s,1); s += __shfl_xor(s,2); s += __shfl_xor(s,4); s += __shfl_xor(s,8);
    int r = r0 + ty*8 + i;
    if(tx==0 && r < g.rows) g.P[r] = s;
  }
}

// ---- CSR build (fused across all 4 groupings) ----
__global__ __launch_bounds__(256) void k_hist(const int* __restrict__ eks, const int* __restrict__ ekd,
      const int* __restrict__ ses, const int* __restrict__ sed,
      int* c_eke, int* c_ekk, int* c_see, int* c_ses){
  int i = blockIdx.x*256 + threadIdx.x;
  if(i < NEK){ atomicAdd(c_eke + eks[i], 1); atomicAdd(c_ekk + (ekd[i]-E_N), 1); }
  if(i < NSE){ atomicAdd(c_see + ses[i], 1); atomicAdd(c_ses + (sed[i]-E_N), 1); }
}

__global__ __launch_bounds__(1024) void k_scan(CSet c0, CSet c1, CSet c2, CSet c3){
  CSet c = c0;
  if(blockIdx.x==1) c=c1; else if(blockIdx.x==2) c=c2; else if(blockIdx.x==3) c=c3;
  __shared__ int part[1024];
  int t = threadIdx.x;
  int n = c.n;
  int chunk = (n + 1023) >> 10;
  int b0 = t * chunk;
  int s = 0;
  for(int i=0;i<chunk;i++){ int idx=b0+i; if(idx<n) s += c.cnt[idx]; }
  part[t] = s;
  __syncthreads();
  for(int off=1; off<1024; off<<=1){
    int v = (t>=off) ? part[t-off] : 0;
    __syncthreads();
    part[t] += v;
    __syncthreads();
  }
  int run = t ? part[t-1] : 0;
  for(int i=0;i<chunk;i++){
    int idx=b0+i;
    if(idx<n){ int cc = c.cnt[idx]; c.rp[idx]=run; c.cur[idx]=run; run += cc; }
  }
  if(t==0) c.rp[n] = part[1023];
}

__global__ __launch_bounds__(256) void k_fill(const int* __restrict__ eks, const int* __restrict__ ekd,
      const int* __restrict__ ses, const int* __restrict__ sed,
      int* u_eke, int* u_ekk, int* u_see, int* u_ses,
      int* o_eke, int* o_ekk, int* o_see, int* o_ses){
  int i = blockIdx.x*256 + threadIdx.x;
  if(i < NEK){
    int a = eks[i], b = ekd[i];
    int pos = atomicAdd(u_eke + a, 1);       o_eke[pos] = b;
    int pos2 = atomicAdd(u_ekk + (b-E_N), 1); o_ekk[pos2] = a;
  }
  if(i < NSE){
    int a = ses[i], b = sed[i];
    int pos = atomicAdd(u_see + a, 1);       o_see[pos] = b;
    int pos2 = atomicAdd(u_ses + (b-E_N), 1); o_ses[pos2] = a;
  }
}

// ---- batched segment softmax-aggregate.
// y<3: 4 rows/block, 1 wave/row, 2 half-wave edge streams, float4 gathers.
// y==3: 1 row/block, 4 waves = 8 streams, LDS combine.
// out[row] = (base? base[row] : 0) + (Σ exp(p[col])·z[col]) / Σ exp(p[col])
// (dst-side score q cancels in per-segment softmax — not computed.)
__global__ __launch_bounds__(256) void k_seg(SSet s0, SSet s1, SSet s2, SSet s3){
  __shared__ float4 red[4][32];
  __shared__ float redd[4];
  SSet s = s0;
  int y = blockIdx.y;
  if(y==1) s=s1; else if(y==2) s=s2; else if(y==3) s=s3;
  int lane = threadIdx.x & 63, wid = threadIdx.x >> 6;
  int half = lane >> 5, l32 = lane & 31;
  bool multi = (y==3);
  int row, str, step;
  if(!multi){ row = blockIdx.x*4 + wid; str = half;       step = 2; }
  else      { row = blockIdx.x;         str = wid*2+half; step = 8; }
  if(row >= s.ndst) return;              // uniform per block for multi
  int e0 = s.rowptr[row], e1 = s.rowptr[row+1];
  const int* col = s.col; const float* p = s.p; const float* z = s.z;
  float4 acc = {0.f,0.f,0.f,0.f}; float den = 0.f;
  int e = e0 + str;
  for(; e + step < e1; e += 2*step){
    int sA = col[e], sB = col[e+step];
    float pA = p[sA], pB = p[sB];
    float4 zA = ((const float4*)(z + (size_t)sA*128))[l32];
    float4 zB = ((const float4*)(z + (size_t)sB*128))[l32];
    float xA = expf(pA), xB = expf(pB);
    acc.x += xA*zA.x + xB*zB.x; acc.y += xA*zA.y + xB*zB.y;
    acc.z += xA*zA.z + xB*zB.z; acc.w += xA*zA.w + xB*zB.w;
    den += xA + xB;
  }
  if(e < e1){
    int sA = col[e];
    float xA = expf(p[sA]);
    float4 zA = ((const float4*)(z + (size_t)sA*128))[l32];
    acc.x += xA*zA.x; acc.y += xA*zA.y; acc.z += xA*zA.z; acc.w += xA*zA.w;
    den += xA;
  }
  acc.x += __shfl_xor(acc.x,32); acc.y += __shfl_xor(acc.y,32);
  acc.z += __shfl_xor(acc.z,32); acc.w += __shfl_xor(acc.w,32);
  den   += __shfl_xor(den,32);
  if(multi){
    if(half==0){ red[wid][l32] = acc; if(l32==0) redd[wid] = den; }
    __syncthreads();
    if(wid) return;
    acc = red[0][l32]; den = redd[0];
    #pragma unroll
    for(int i=1;i<4;i++){
      float4 r4 = red[i][l32];
      acc.x+=r4.x; acc.y+=r4.y; acc.z+=r4.z; acc.w+=r4.w; den += redd[i];
    }
  }
  float inv = den > 0.f ? 1.f/den : 0.f;
  float4 res = {acc.x*inv, acc.y*inv, acc.z*inv, acc.w*inv};
  if(s.base){
    float4 b4 = ((const float4*)(s.base + (size_t)row*128))[l32];
    res.x+=b4.x; res.y+=b4.y; res.z+=b4.z; res.w+=b4.w;
  }
  if(half==0) ((float4*)(s.out + (size_t)row*128))[l32] = res;
}

// ---- per-exercise gate: sc = softmax([s1,s2]); ex = base + sc0*Bx + sc1*Cx ----
__global__ __launch_bounds__(256) void k_exup(const float* __restrict__ base, float* __restrict__ ex,
     const float* __restrict__ Bx, const float* __restrict__ Cx,
     const float* __restrict__ Fw, const float* __restrict__ Fb){
  int w = (blockIdx.x*256 + threadIdx.x) >> 6;
  int lane = threadIdx.x & 63;
  if(w >= E_N) return;
  const float* er = base + (size_t)w*128;
  const float* br = Bx + (size_t)w*128;
  const float* cr = Cx + (size_t)w*128;
  float e0 = er[lane], e1 = er[lane+64];
  float b0 = br[lane], b1 = br[lane+64];
  float c0 = cr[lane], c1 = cr[lane+64];
  float s1 = e0*Fw[lane]     + e1*Fw[lane+64]
           + b0*Fw[lane+128] + b1*Fw[lane+192];
  float s2 = e0*Fw[256+lane]     + e1*Fw[256+lane+64]
           + c0*Fw[256+lane+128] + c1*Fw[256+lane+192];
  #pragma unroll
  for(int off=32; off; off>>=1){ s1 += __shfl_down(s1,off); s2 += __shfl_down(s2,off); }
  s1 = __shfl(s1, 0) + Fb[0];
  s2 = __shfl(s2, 0) + Fb[1];
  float mx = fmaxf(s1,s2);
  float pp = expf(s1-mx), qq = expf(s2-mx);
  float inv = 1.f/(pp+qq);
  float* orow = ex + (size_t)w*128;
  orow[lane]    = e0 + (pp*inv)*b0 + (qq*inv)*c0;
  orow[lane+64] = e1 + (pp*inv)*b1 + (qq*inv)*c1;
}

// ---- fused outputs: stu_ts, exer_ts, kn_ts (2 rows/wave, float4) + disc ----
__global__ __launch_bounds__(256) void k_out(const float* __restrict__ st, const float* __restrict__ ex,
    const float* __restrict__ kn, const float* __restrict__ disc,
    const int* __restrict__ sid, const int* __restrict__ eid,
    float* out0, float* out1, float* out2, float* out3){
  int w = (blockIdx.x*256 + threadIdx.x) >> 6;
  int lane = threadIdx.x & 63;
  const int ROWW = 3*B_N*64;     // waves for matrix rows (2 rows/wave)
  if(w < ROWW){
    int half = lane>>5, l32 = lane&31;
    int r = w*2 + half;          // 0 .. 3*262144
    int sec = r >> 18;           // B_N*128 = 262144 = 2^18
    int rr = r & 262143;
    int b = rr >> 7, i = rr & 127;
    const float* emb; int srow; float* ob;
    if(sec==0){ emb=st; srow=sid[b]; ob=out0; }
    else if(sec==1){ emb=ex; srow=eid[b]; ob=out1; }
    else { emb=kn; srow=i; ob=out3; }
    float4 v = ((const float4*)(emb + (size_t)srow*128))[l32];
    ((float4*)(ob + (size_t)rr*128))[l32] = v;
  } else {
    int i = (w - ROWW)*64 + lane;
    if(i < B_N) out2[i] = disc[eid[i]];
  }
}

extern "C" void kernel_launch(void* const* d_in, const int* in_sizes, int n_in,
                              void* d_out, int out_size, void* d_ws, size_t ws_size,
                              hipStream_t stream){
  (void)in_sizes; (void)out_size; (void)ws_size;
  const float* stu_emb  = (const float*)d_in[0];
  const float* exer_emb = (const float*)d_in[1];
  const float* kn_emb   = (const float*)d_in[2];
  const float* disc_emb = (const float*)d_in[3];
  const float* GW = (const float*)d_in[4];
  const float* Ga = (const float*)d_in[5];
  const float* Fw = (const float*)d_in[6];
  const float* Fb = (const float*)d_in[7];
  int base = n_in - 6;
  const int* sid    = (const int*)d_in[base];
  const int* eid    = (const int*)d_in[base+1];
  const int* ek_src = (const int*)d_in[base+2];
  const int* ek_dst = (const int*)d_in[base+3];
  const int* se_src = (const int*)d_in[base+4];
  const int* se_dst = (const int*)d_in[base+5];

  char* w = (char*)d_ws;
  size_t off = 0;
  auto alloc = [&](size_t bytes)->char*{ char* p = w + off; off += (bytes + 255) & ~(size_t)255; return p; };
  float* st_f = (float*)alloc((size_t)S_N*D_N*4);
  float* ex_f = (float*)alloc((size_t)E_N*D_N*4);
  float* kn_f = (float*)alloc((size_t)K_N*D_N*4);
  float* Bx   = (float*)alloc((size_t)E_N*D_N*4);
  float* Cx   = (float*)alloc((size_t)E_N*D_N*4);
  float* zefk = (float*)alloc((size_t)K_N*D_N*4);   // kn z (node ids E..E+K)
  float* zkfe = (float*)alloc((size_t)E_N*D_N*4);   // ex z
  float* zefu = (float*)alloc((size_t)S_N*D_N*4);   // st z (node ids E..E+S)
  float* zufe = (float*)alloc((size_t)E_N*D_N*4);   // ex z
  float* pefk = (float*)alloc((size_t)K_N*4);
  float* pkfe = (float*)alloc((size_t)E_N*4);
  float* pefu = (float*)alloc((size_t)S_N*4);
  float* pufe = (float*)alloc((size_t)E_N*4);
  int*   cnt  = (int*)alloc((size_t)(2*E_N+K_N+S_N)*4);
  int*   rp   = (int*)alloc((size_t)(2*(E_N+1)+(K_N+1)+(S_N+1))*4);
  int*   cur  = (int*)alloc((size_t)(2*E_N+K_N+S_N)*4);
  int*   col  = (int*)alloc((size_t)(2*NEK+2*NSE)*4);

  int* cnt_eke = cnt;                 int* cnt_ekk = cnt + E_N;
  int* cnt_see = cnt + E_N + K_N;     int* cnt_ses = cnt + 2*E_N + K_N;
  int* cur_eke = cur;                 int* cur_ekk = cur + E_N;
  int* cur_see = cur + E_N + K_N;     int* cur_ses = cur + 2*E_N + K_N;
  int* rp_eke = rp;                                int* rp_ekk = rp + (E_N+1);
  int* rp_see = rp + (E_N+1) + (K_N+1);            int* rp_ses = rp + 2*(E_N+1) + (K_N+1);
  int* col_eke = col;                 int* col_ekk = col + NEK;
  int* col_see = col + 2*NEK;         int* col_ses = col + 2*NEK + NSE;

  // ---- CSR build: 4 dispatches total ----
  hipMemsetAsync(cnt, 0, (size_t)(2*E_N+K_N+S_N)*4, stream);
  const int gb = (NSE+255)/256;
  k_hist<<<gb,256,0,stream>>>(ek_src, ek_dst, se_src, se_dst, cnt_eke, cnt_ekk, cnt_see, cnt_ses);
  k_scan<<<4,1024,0,stream>>>(CSet{cnt_eke,E_N,rp_eke,cur_eke}, CSet{cnt_ekk,K_N,rp_ekk,cur_ekk},
                              CSet{cnt_see,E_N,rp_see,cur_see}, CSet{cnt_ses,S_N,rp_ses,cur_ses});
  k_fill<<<gb,256,0,stream>>>(ek_src, ek_dst, se_src, se_dst,
                              cur_eke, cur_ekk, cur_see, cur_ses,
                              col_eke, col_ekk, col_see, col_ses);

  for(int l=0; l<2; l++){
    const float* knp = l ? kn_f : kn_emb;
    const float* exp_ = l ? ex_f : exer_emb;
    const float* stp = l ? st_f : stu_emb;
    // all 4 gemms read pre-layer state -> one batched dispatch
    GSet g0{knp,  GW + (size_t)(l*4+1)*16384, Ga + (size_t)(l*4+1)*256, zefk, pefk, K_N};
    GSet g1{exp_, GW + (size_t)(l*4+0)*16384, Ga + (size_t)(l*4+0)*256, zkfe, pkfe, E_N};
    GSet g2{stp,  GW + (size_t)(l*4+3)*16384, Ga + (size_t)(l*4+3)*256, zefu, pefu, S_N};
    GSet g3{exp_, GW + (size_t)(l*4+2)*16384, Ga + (size_t)(l*4+2)*256, zufe, pufe, E_N};
    dim3 gg((S_N+127)/128, 4);
    k_gemm<<<gg,256,0,stream>>>(g0,g1,g2,g3);
    // all 4 aggregations independent -> one batched dispatch
    SSet s0{zefk - (size_t)E_N*128, pefk - E_N, rp_eke, col_eke, nullptr, Bx,   E_N};  // efk -> Bx
    SSet s1{zefu - (size_t)E_N*128, pefu - E_N, rp_see, col_see, nullptr, Cx,   E_N};  // efu -> Cx
    SSet s2{zufe,                   pufe,       rp_ses, col_ses, stp,     st_f, S_N};  // ufe -> st
    SSet s3{zkfe,                   pkfe,       rp_ekk, col_ekk, knp,     kn_f, K_N};  // kfe -> kn (multi-wave)
    dim3 sg((S_N+3)/4, 4);
    k_seg<<<sg,256,0,stream>>>(s0,s1,s2,s3);
    k_exup<<<(E_N*64)/256,256,0,stream>>>(exp_, ex_f, Bx, Cx, Fw + (size_t)l*3*2*D_N, Fb + (size_t)l*3);
  }

  float* out  = (float*)d_out;
  float* out0 = out;                           // stu_ts  (B,D,D)
  float* out1 = out0 + (size_t)B_N*D_N*D_N;    // exer_ts (B,D,D)
  float* out2 = out1 + (size_t)B_N*D_N*D_N;    // disc    (B,1)
  float* out3 = out2 + (size_t)B_N;            // kn_ts   (B,K,D)
  int waves = 3*B_N*64 + 32;
  k_out<<<(waves+3)/4,256,0,stream>>>(st_f, ex_f, kn_f, disc_emb, sid, eid, out0, out1, out2, out3);
}

// Round 4
// 798.545 us; speedup vs baseline: 4.3914x; 1.1602x over previous
//
#include <hip/hip_runtime.h>

#define S_N 20000
#define E_N 10000
#define K_N 128
#define D_N 128
#define NEK 40000
#define NSE 500000
#define B_N 2048

typedef __attribute__((ext_vector_type(8))) short bf16x8;
typedef __attribute__((ext_vector_type(4))) float f32x4;

__device__ __forceinline__ unsigned short f2bf(float f){
  unsigned int u = __float_as_uint(f);
  unsigned int r = u + 0x7FFFu + ((u >> 16) & 1u);   // RNE to bf16
  return (unsigned short)(r >> 16);
}
__device__ __forceinline__ float bf2f(unsigned short h){
  return __uint_as_float(((unsigned int)h) << 16);
}

struct GS { const unsigned short* Ah; const unsigned short* Al;
            const unsigned short* Wh; const unsigned short* Wl;
            float* Z; int rows; };
struct SSet { const float* z; const float* p; const int* rowptr; const int* col;
              const float* base; float* out; int ndst; };
struct CSet { const int* cnt; int n; int* rp; int* cur; };

// ---- W prep: per gate, emit MFMA-lane-layout bf16 hi/lo fragments + wa = W@a1 ----
// frag layout: wf[gate][pi=c2*4+kt][lane][j] ; B-operand lane map: n=l&15, k=(l>>4)*8+j
__global__ __launch_bounds__(256) void k_wprep(const float* __restrict__ GW, const float* __restrict__ Ga,
                                               unsigned short* __restrict__ wf, float* __restrict__ wa){
  int g = blockIdx.x;                       // gate 0..7
  const float* W  = GW + (size_t)g*16384;
  const float* a1 = Ga + (size_t)g*256;     // src-half of attention vector
  unsigned short* whi = wf + (size_t)g*16384;
  unsigned short* wlo = wf + (size_t)(8+g)*16384;
  int t = threadIdx.x, l = t & 63;
  for(int pi = t>>6; pi < 32; pi += 4){
    int c2 = pi >> 2, kt = pi & 3;
    unsigned short h[8], lo[8];
    #pragma unroll
    for(int j=0;j<8;j++){
      int k = kt*32 + (l>>4)*8 + j;
      int c = c2*16 + (l&15);
      float f = W[(size_t)k*128 + c];
      unsigned short hb = f2bf(f);
      h[j] = hb; lo[j] = f2bf(f - bf2f(hb));
    }
    size_t off = ((size_t)pi*64 + l)*8;
    uint4 hv, lv;
    hv.x = (unsigned)h[0] | ((unsigned)h[1]<<16);  hv.y = (unsigned)h[2] | ((unsigned)h[3]<<16);
    hv.z = (unsigned)h[4] | ((unsigned)h[5]<<16);  hv.w = (unsigned)h[6] | ((unsigned)h[7]<<16);
    lv.x = (unsigned)lo[0] | ((unsigned)lo[1]<<16); lv.y = (unsigned)lo[2] | ((unsigned)lo[3]<<16);
    lv.z = (unsigned)lo[4] | ((unsigned)lo[5]<<16); lv.w = (unsigned)lo[6] | ((unsigned)lo[7]<<16);
    *(uint4*)(whi + off) = hv;
    *(uint4*)(wlo + off) = lv;
  }
  for(int k = t; k < 128; k += 256){        // wa[k] = sum_c W[k][c]*a1[c]
    float s = 0.f;
    const float* wr = W + (size_t)k*128;
    for(int c=0;c<128;c++) s += wr[c]*a1[c];
    wa[(size_t)g*128 + k] = s;
  }
}

// ---- per-layer state convert: f32 -> bf16 hi/lo + P = exp(h·wa) per gate ----
__global__ __launch_bounds__(256) void k_cvt(const float* __restrict__ kn, const float* __restrict__ ex,
    const float* __restrict__ st,
    unsigned short* __restrict__ knb, unsigned short* __restrict__ exb, unsigned short* __restrict__ stb,
    const float* __restrict__ wa, int l4,
    float* __restrict__ Pefk, float* __restrict__ Pkfe, float* __restrict__ Pufe, float* __restrict__ Pefu){
  int w = (blockIdx.x*256 + threadIdx.x) >> 6;
  int lane = threadIdx.x & 63;
  const float* src; unsigned short *hi, *lo; int r;
  const float* wv1; const float* wv2 = nullptr; float *P1, *P2 = nullptr;
  if(w < K_N){ r = w; src = kn + (size_t)r*128; hi = knb; lo = knb + (size_t)K_N*128;
               wv1 = wa + (size_t)(l4+1)*128; P1 = Pefk; }
  else if(w < K_N + E_N){ r = w - K_N; src = ex + (size_t)r*128; hi = exb; lo = exb + (size_t)E_N*128;
               wv1 = wa + (size_t)(l4+0)*128; P1 = Pkfe;
               wv2 = wa + (size_t)(l4+2)*128; P2 = Pufe; }
  else { r = w - K_N - E_N; if(r >= S_N) return; src = st + (size_t)r*128; hi = stb; lo = stb + (size_t)S_N*128;
               wv1 = wa + (size_t)(l4+3)*128; P1 = Pefu; }
  float2 x = ((const float2*)src)[lane];
  float2 v1 = ((const float2*)wv1)[lane];
  float d1 = x.x*v1.x + x.y*v1.y;
  float d2 = 0.f;
  if(wv2){ float2 v2 = ((const float2*)wv2)[lane]; d2 = x.x*v2.x + x.y*v2.y; }
  #pragma unroll
  for(int off=1; off<64; off<<=1){ d1 += __shfl_xor(d1,off); d2 += __shfl_xor(d2,off); }
  if(lane==0){ P1[r] = expf(d1); if(P2) P2[r] = expf(d2); }
  unsigned short h0 = f2bf(x.x), h1 = f2bf(x.y);
  unsigned short l0 = f2bf(x.x - bf2f(h0)), l1 = f2bf(x.y - bf2f(h1));
  ((ushort2*)(hi + (size_t)r*128))[lane] = make_ushort2(h0,h1);
  ((ushort2*)(lo + (size_t)r*128))[lane] = make_ushort2(l0,l1);
}

// ---- split-bf16 MFMA GEMM: Z[r][c] = A[r][:]@W[:][c], fp32-accurate via hi/lo 3-pass ----
// block = 4 waves; wave w = 32-col tile; block tile = 32 rows x 128 cols; no LDS.
#define GT0 4
#define GT1 317
#define GT2 942
#define GT3 1255
__global__ __launch_bounds__(256) void k_gemm(GS g0, GS g1, GS g2, GS g3){
  int b = blockIdx.x;
  GS g; int lt;
  if(b < GT0){ g = g0; lt = b; }
  else if(b < GT1){ g = g1; lt = b - GT0; }
  else if(b < GT2){ g = g2; lt = b - GT1; }
  else { g = g3; lt = b - GT2; }
  int l = threadIdx.x & 63, wv = threadIdx.x >> 6;
  int r0 = lt*32;
  // W fragments for this wave's 32 cols: 2 col-subtiles x 4 k-tiles, hi+lo
  bf16x8 bh[2][4], bl[2][4];
  #pragma unroll
  for(int cs=0; cs<2; cs++)
    #pragma unroll
    for(int kt=0; kt<4; kt++){
      size_t o = (((size_t)((wv*2+cs)*4 + kt))*64 + l)*8;
      bh[cs][kt] = *(const bf16x8*)(g.Wh + o);
      bl[cs][kt] = *(const bf16x8*)(g.Wl + o);
    }
  f32x4 acc[2][2];
  #pragma unroll
  for(int rs=0;rs<2;rs++)
    #pragma unroll
    for(int cs=0;cs<2;cs++) acc[rs][cs] = (f32x4){0.f,0.f,0.f,0.f};
  #pragma unroll
  for(int kt=0; kt<4; kt++){
    bf16x8 ah[2], al[2];
    #pragma unroll
    for(int rs=0; rs<2; rs++){
      size_t ao = ((size_t)(r0 + rs*16 + (l&15)))*128 + kt*32 + (l>>4)*8;
      ah[rs] = *(const bf16x8*)(g.Ah + ao);
      al[rs] = *(const bf16x8*)(g.Al + ao);
    }
    #pragma unroll
    for(int rs=0; rs<2; rs++)
      #pragma unroll
      for(int cs=0; cs<2; cs++){
        acc[rs][cs] = __builtin_amdgcn_mfma_f32_16x16x32_bf16(ah[rs], bh[cs][kt], acc[rs][cs], 0,0,0);
        acc[rs][cs] = __builtin_amdgcn_mfma_f32_16x16x32_bf16(ah[rs], bl[cs][kt], acc[rs][cs], 0,0,0);
        acc[rs][cs] = __builtin_amdgcn_mfma_f32_16x16x32_bf16(al[rs], bh[cs][kt], acc[rs][cs], 0,0,0);
      }
  }
  // C/D layout: col = lane&15, row = (lane>>4)*4 + j   [m89-verified]
  #pragma unroll
  for(int rs=0; rs<2; rs++)
    #pragma unroll
    for(int cs=0; cs<2; cs++){
      int cb = (wv<<5) + (cs<<4) + (l&15);
      #pragma unroll
      for(int j=0;j<4;j++){
        int rr = r0 + rs*16 + ((l>>4)<<2) + j;
        if(rr < g.rows) g.Z[(size_t)rr*128 + cb] = acc[rs][cs][j];
      }
    }
}

// ---- CSR build ----
__global__ __launch_bounds__(256) void k_hist(const int* __restrict__ eks, const int* __restrict__ ekd,
      const int* __restrict__ ses, const int* __restrict__ sed,
      int* c_eke, int* c_ekk, int* c_see, int* c_ses){
  int i = blockIdx.x*256 + threadIdx.x;
  if(i < NEK){ atomicAdd(c_eke + eks[i], 1); atomicAdd(c_ekk + (ekd[i]-E_N), 1); }
  if(i < NSE){ atomicAdd(c_see + ses[i], 1); atomicAdd(c_ses + (sed[i]-E_N), 1); }
}

__global__ __launch_bounds__(1024) void k_scan(CSet c0, CSet c1, CSet c2, CSet c3){
  CSet c = c0;
  if(blockIdx.x==1) c=c1; else if(blockIdx.x==2) c=c2; else if(blockIdx.x==3) c=c3;
  __shared__ int part[1024];
  int t = threadIdx.x;
  int n = c.n;
  int chunk = (n + 1023) >> 10;
  int b0 = t * chunk;
  int s = 0;
  for(int i=0;i<chunk;i++){ int idx=b0+i; if(idx<n) s += c.cnt[idx]; }
  part[t] = s;
  __syncthreads();
  for(int off=1; off<1024; off<<=1){
    int v = (t>=off) ? part[t-off] : 0;
    __syncthreads();
    part[t] += v;
    __syncthreads();
  }
  int run = t ? part[t-1] : 0;
  for(int i=0;i<chunk;i++){
    int idx=b0+i;
    if(idx<n){ int cc = c.cnt[idx]; c.rp[idx]=run; c.cur[idx]=run; run += cc; }
  }
  if(t==0) c.rp[n] = part[1023];
}

__global__ __launch_bounds__(256) void k_fill(const int* __restrict__ eks, const int* __restrict__ ekd,
      const int* __restrict__ ses, const int* __restrict__ sed,
      int* u_eke, int* u_ekk, int* u_see, int* u_ses,
      int* o_eke, int* o_ekk, int* o_see, int* o_ses){
  int i = blockIdx.x*256 + threadIdx.x;
  if(i < NEK){
    int a = eks[i], b = ekd[i];
    int pos = atomicAdd(u_eke + a, 1);        o_eke[pos] = b;
    int pos2 = atomicAdd(u_ekk + (b-E_N), 1); o_ekk[pos2] = a;
  }
  if(i < NSE){
    int a = ses[i], b = sed[i];
    int pos = atomicAdd(u_see + a, 1);        o_see[pos] = b;
    int pos2 = atomicAdd(u_ses + (b-E_N), 1); o_ses[pos2] = a;
  }
}

// ---- segment softmax-aggregate (p pre-exponentiated). Flattened grid:
// [0,2500) s0; [2500,5000) s1; [5000,10000) s2: 4 rows/block, 1 wave/row,
// 2 half-wave streams, unroll-4. [10000,10128) s3: 1 row/block, 8 streams.
#define SB1 2500
#define SB2 5000
#define SB3 10000
#define SB4 10128
__global__ __launch_bounds__(256) void k_seg(SSet s0, SSet s1, SSet s2, SSet s3){
  __shared__ float4 red[4][32];
  __shared__ float redd[4];
  int b = blockIdx.x;
  int lane = threadIdx.x & 63, wid = threadIdx.x >> 6;
  int half = lane >> 5, l32 = lane & 31;
  SSet s; int row, str, stride; bool multi = false;
  if(b < SB1){ s = s0; row = b*4 + wid; }
  else if(b < SB2){ s = s1; row = (b-SB1)*4 + wid; }
  else if(b < SB3){ s = s2; row = (b-SB2)*4 + wid; }
  else { s = s3; row = b - SB3; multi = true; }
  if(!multi){ str = half; stride = 2; }
  else      { str = wid*2 + half; stride = 8; }
  if(row >= s.ndst) return;
  int e0 = s.rowptr[row], e1 = s.rowptr[row+1];
  const int* col = s.col; const float* p = s.p; const float* z = s.z;
  float4 acc = {0.f,0.f,0.f,0.f}; float den = 0.f;
  int e = e0 + str;
  for(; e + 3*stride < e1; e += 4*stride){
    int cA = col[e], cB = col[e+stride], cC = col[e+2*stride], cD = col[e+3*stride];
    float xA = p[cA], xB = p[cB], xC = p[cC], xD = p[cD];
    float4 zA = ((const float4*)(z + (size_t)cA*128))[l32];
    float4 zB = ((const float4*)(z + (size_t)cB*128))[l32];
    float4 zC = ((const float4*)(z + (size_t)cC*128))[l32];
    float4 zD = ((const float4*)(z + (size_t)cD*128))[l32];
    acc.x += xA*zA.x + xB*zB.x + xC*zC.x + xD*zD.x;
    acc.y += xA*zA.y + xB*zB.y + xC*zC.y + xD*zD.y;
    acc.z += xA*zA.z + xB*zB.z + xC*zC.z + xD*zD.z;
    acc.w += xA*zA.w + xB*zB.w + xC*zC.w + xD*zD.w;
    den += (xA + xB) + (xC + xD);
  }
  for(; e < e1; e += stride){
    int cA = col[e];
    float xA = p[cA];
    float4 zA = ((const float4*)(z + (size_t)cA*128))[l32];
    acc.x += xA*zA.x; acc.y += xA*zA.y; acc.z += xA*zA.z; acc.w += xA*zA.w;
    den += xA;
  }
  acc.x += __shfl_xor(acc.x,32); acc.y += __shfl_xor(acc.y,32);
  acc.z += __shfl_xor(acc.z,32); acc.w += __shfl_xor(acc.w,32);
  den   += __shfl_xor(den,32);
  if(multi){
    if(half==0){ red[wid][l32] = acc; if(l32==0) redd[wid] = den; }
    __syncthreads();
    if(wid) return;
    acc = red[0][l32]; den = redd[0];
    #pragma unroll
    for(int i=1;i<4;i++){
      float4 r4 = red[i][l32];
      acc.x+=r4.x; acc.y+=r4.y; acc.z+=r4.z; acc.w+=r4.w; den += redd[i];
    }
  }
  float inv = den > 0.f ? 1.f/den : 0.f;
  float4 res = {acc.x*inv, acc.y*inv, acc.z*inv, acc.w*inv};
  if(s.base){
    float4 b4 = ((const float4*)(s.base + (size_t)row*128))[l32];
    res.x+=b4.x; res.y+=b4.y; res.z+=b4.z; res.w+=b4.w;
  }
  if(half==0) ((float4*)(s.out + (size_t)row*128))[l32] = res;
}

// ---- per-exercise gate: sc = softmax([s1,s2]); ex = base + sc0*Bx + sc1*Cx ----
__global__ __launch_bounds__(256) void k_exup(const float* __restrict__ base, float* __restrict__ ex,
     const float* __restrict__ Bx, const float* __restrict__ Cx,
     const float* __restrict__ Fw, const float* __restrict__ Fb){
  int w = (blockIdx.x*256 + threadIdx.x) >> 6;
  int lane = threadIdx.x & 63;
  if(w >= E_N) return;
  const float* er = base + (size_t)w*128;
  const float* br = Bx + (size_t)w*128;
  const float* cr = Cx + (size_t)w*128;
  float e0 = er[lane], e1 = er[lane+64];
  float b0 = br[lane], b1 = br[lane+64];
  float c0 = cr[lane], c1 = cr[lane+64];
  float s1 = e0*Fw[lane]     + e1*Fw[lane+64]
           + b0*Fw[lane+128] + b1*Fw[lane+192];
  float s2 = e0*Fw[256+lane]     + e1*Fw[256+lane+64]
           + c0*Fw[256+lane+128] + c1*Fw[256+lane+192];
  #pragma unroll
  for(int off=32; off; off>>=1){ s1 += __shfl_down(s1,off); s2 += __shfl_down(s2,off); }
  s1 = __shfl(s1, 0) + Fb[0];
  s2 = __shfl(s2, 0) + Fb[1];
  float mx = fmaxf(s1,s2);
  float pp = expf(s1-mx), qq = expf(s2-mx);
  float inv = 1.f/(pp+qq);
  float* orow = ex + (size_t)w*128;
  orow[lane]    = e0 + (pp*inv)*b0 + (qq*inv)*c0;
  orow[lane+64] = e1 + (pp*inv)*b1 + (qq*inv)*c1;
}

// ---- fused outputs ----
__global__ __launch_bounds__(256) void k_out(const float* __restrict__ st, const float* __restrict__ ex,
    const float* __restrict__ kn, const float* __restrict__ disc,
    const int* __restrict__ sid, const int* __restrict__ eid,
    float* out0, float* out1, float* out2, float* out3){
  int w = (blockIdx.x*256 + threadIdx.x) >> 6;
  int lane = threadIdx.x & 63;
  const int ROWW = 3*B_N*64;
  if(w < ROWW){
    int half = lane>>5, l32 = lane&31;
    int r = w*2 + half;
    int sec = r >> 18;              // B_N*128 = 2^18
    int rr = r & 262143;
    int b = rr >> 7, i = rr & 127;
    const float* emb; int srow; float* ob;
    if(sec==0){ emb=st; srow=sid[b]; ob=out0; }
    else if(sec==1){ emb=ex; srow=eid[b]; ob=out1; }
    else { emb=kn; srow=i; ob=out3; }
    f32x4 v = *((const f32x4*)(emb + (size_t)srow*128) + l32);
    __builtin_nontemporal_store(v, (f32x4*)(ob + (size_t)rr*128) + l32);
  } else {
    int i = (w - ROWW)*64 + lane;
    if(i < B_N) out2[i] = disc[eid[i]];
  }
}

extern "C" void kernel_launch(void* const* d_in, const int* in_sizes, int n_in,
                              void* d_out, int out_size, void* d_ws, size_t ws_size,
                              hipStream_t stream){
  (void)in_sizes; (void)out_size; (void)ws_size;
  const float* stu_emb  = (const float*)d_in[0];
  const float* exer_emb = (const float*)d_in[1];
  const float* kn_emb   = (const float*)d_in[2];
  const float* disc_emb = (const float*)d_in[3];
  const float* GW = (const float*)d_in[4];
  const float* Ga = (const float*)d_in[5];
  const float* Fw = (const float*)d_in[6];
  const float* Fb = (const float*)d_in[7];
  int base = n_in - 6;
  const int* sid    = (const int*)d_in[base];
  const int* eid    = (const int*)d_in[base+1];
  const int* ek_src = (const int*)d_in[base+2];
  const int* ek_dst = (const int*)d_in[base+3];
  const int* se_src = (const int*)d_in[base+4];
  const int* se_dst = (const int*)d_in[base+5];

  char* w = (char*)d_ws;
  size_t off = 0;
  auto alloc = [&](size_t bytes)->char*{ char* p = w + off; off += (bytes + 255) & ~(size_t)255; return p; };
  float* st_f = (float*)alloc((size_t)S_N*D_N*4);
  float* ex_f = (float*)alloc((size_t)E_N*D_N*4);
  float* kn_f = (float*)alloc((size_t)K_N*D_N*4);
  float* Bx   = (float*)alloc((size_t)E_N*D_N*4);
  float* Cx   = (float*)alloc((size_t)E_N*D_N*4);
  float* zefk = (float*)alloc((size_t)K_N*D_N*4);
  float* zkfe = (float*)alloc((size_t)E_N*D_N*4);
  float* zefu = (float*)alloc((size_t)S_N*D_N*4);
  float* zufe = (float*)alloc((size_t)E_N*D_N*4);
  float* Pefk = (float*)alloc((size_t)K_N*4);
  float* Pkfe = (float*)alloc((size_t)E_N*4);
  float* Pefu = (float*)alloc((size_t)S_N*4);
  float* Pufe = (float*)alloc((size_t)E_N*4);
  unsigned short* knb = (unsigned short*)alloc((size_t)K_N*D_N*2*2 + 4096);
  unsigned short* exb = (unsigned short*)alloc((size_t)E_N*D_N*2*2 + 4096);
  unsigned short* stb = (unsigned short*)alloc((size_t)S_N*D_N*2*2 + 4096);
  unsigned short* wf  = (unsigned short*)alloc((size_t)16*16384*2);
  float* wa   = (float*)alloc((size_t)8*128*4);
  int*   cnt  = (int*)alloc((size_t)(2*E_N+K_N+S_N)*4);
  int*   rp   = (int*)alloc((size_t)(2*(E_N+1)+(K_N+1)+(S_N+1))*4);
  int*   cur  = (int*)alloc((size_t)(2*E_N+K_N+S_N)*4);
  int*   col  = (int*)alloc((size_t)(2*NEK+2*NSE)*4);

  int* cnt_eke = cnt;                 int* cnt_ekk = cnt + E_N;
  int* cnt_see = cnt + E_N + K_N;     int* cnt_ses = cnt + 2*E_N + K_N;
  int* cur_eke = cur;                 int* cur_ekk = cur + E_N;
  int* cur_see = cur + E_N + K_N;     int* cur_ses = cur + 2*E_N + K_N;
  int* rp_eke = rp;                                int* rp_ekk = rp + (E_N+1);
  int* rp_see = rp + (E_N+1) + (K_N+1);            int* rp_ses = rp + 2*(E_N+1) + (K_N+1);
  int* col_eke = col;                 int* col_ekk = col + NEK;
  int* col_see = col + 2*NEK;         int* col_ses = col + 2*NEK + NSE;

  // ---- setup: W prep + CSR build ----
  hipMemsetAsync(cnt, 0, (size_t)(2*E_N+K_N+S_N)*4, stream);
  k_wprep<<<8,256,0,stream>>>(GW, Ga, wf, wa);
  const int gb = (NSE+255)/256;
  k_hist<<<gb,256,0,stream>>>(ek_src, ek_dst, se_src, se_dst, cnt_eke, cnt_ekk, cnt_see, cnt_ses);
  k_scan<<<4,1024,0,stream>>>(CSet{cnt_eke,E_N,rp_eke,cur_eke}, CSet{cnt_ekk,K_N,rp_ekk,cur_ekk},
                              CSet{cnt_see,E_N,rp_see,cur_see}, CSet{cnt_ses,S_N,rp_ses,cur_ses});
  k_fill<<<gb,256,0,stream>>>(ek_src, ek_dst, se_src, se_dst,
                              cur_eke, cur_ekk, cur_see, cur_ses,
                              col_eke, col_ekk, col_see, col_ses);

  const unsigned short* knb_lo = knb + (size_t)K_N*128;
  const unsigned short* exb_lo = exb + (size_t)E_N*128;
  const unsigned short* stb_lo = stb + (size_t)S_N*128;

  for(int l=0; l<2; l++){
    const float* knp = l ? kn_f : kn_emb;
    const float* exp_ = l ? ex_f : exer_emb;
    const float* stp = l ? st_f : stu_emb;
    int l4 = l*4;
    // state -> bf16 hi/lo + pre-exp'd attention scores
    k_cvt<<<(K_N+E_N+S_N)/4,256,0,stream>>>(knp, exp_, stp, knb, exb, stb, wa, l4,
                                            Pefk, Pkfe, Pufe, Pefu);
    // 4 gemms, one dispatch: gates (l4+1: kn), (l4+0: ex), (l4+3: st), (l4+2: ex)
    GS g0{knb, knb_lo, wf + (size_t)(l4+1)*16384, wf + (size_t)(8+l4+1)*16384, zefk, K_N};
    GS g1{exb, exb_lo, wf + (size_t)(l4+0)*16384, wf + (size_t)(8+l4+0)*16384, zkfe, E_N};
    GS g2{stb, stb_lo, wf + (size_t)(l4+3)*16384, wf + (size_t)(8+l4+3)*16384, zefu, S_N};
    GS g3{exb, exb_lo, wf + (size_t)(l4+2)*16384, wf + (size_t)(8+l4+2)*16384, zufe, E_N};
    k_gemm<<<GT3,256,0,stream>>>(g0,g1,g2,g3);
    // 4 aggregations, one dispatch
    SSet s0{zefk - (size_t)E_N*128, Pefk - E_N, rp_eke, col_eke, nullptr, Bx,   E_N};  // efk -> Bx
    SSet s1{zefu - (size_t)E_N*128, Pefu - E_N, rp_see, col_see, nullptr, Cx,   E_N};  // efu -> Cx
    SSet s2{zufe,                   Pufe,       rp_ses, col_ses, stp,     st_f, S_N};  // ufe -> st
    SSet s3{zkfe,                   Pkfe,       rp_ekk, col_ekk, knp,     kn_f, K_N};  // kfe -> kn
    k_seg<<<SB4,256,0,stream>>>(s0,s1,s2,s3);
    k_exup<<<(E_N*64)/256,256,0,stream>>>(exp_, ex_f, Bx, Cx, Fw + (size_t)l*3*2*D_N, Fb + (size_t)l*3);
  }

  float* out  = (float*)d_out;
  float* out0 = out;                           // stu_ts  (B,D,D)
  float* out1 = out0 + (size_t)B_N*D_N*D_N;    // exer_ts (B,D,D)
  float* out2 = out1 + (size_t)B_N*D_N*D_N;    // disc    (B,1)
  float* out3 = out2 + (size_t)B_N;            // kn_ts   (B,K,D)
  int waves = 3*B_N*64 + 32;
  k_out<<<(waves+3)/4,256,0,stream>>>(st_f, ex_f, kn_f, disc_emb, sid, eid, out0, out1, out2, out3);
}